// Round 9
// baseline (684.829 us; speedup 1.0000x reference)
//
#include <hip/hip_runtime.h>
#include <hip/hip_bf16.h>

#define N_NODES 100000
#define N_EDGES 3200000
#define NGRAPH 1024
#define KTOP 30
#define PELEM (NGRAPH * KTOP * 97)         // pooled tensor elements

#define NBKT 782                            // ceil(100000 / 128) node buckets
#define NBKT_PAD 392                        // padded tile-count row (>= NTILE)
#define NTILE 391                           // edge tiles
#define TILE 8192                           // edges per tile (391*8192 >= 3.2M)

typedef __hip_bfloat16 bf16;

__device__ __forceinline__ float u2f(unsigned short h) {
    return __uint_as_float(((unsigned int)h) << 16);
}
// Flag-steered scalar load of a float-tensor input that may be bf16 or f32.
__device__ __forceinline__ float LD(const void* p, int i, int bf) {
    if (bf) return u2f(((const unsigned short*)p)[i]);
    return ((const float*)p)[i];
}

// ---------- dtype probe ----------
__global__ void k_detect(const void* w1, int* flag) {
    if (threadIdx.x == 0 && blockIdx.x == 0) {
        const unsigned short* u = (const unsigned short*)w1;
        int plausible = 0;
        for (int i = 0; i < 64; i++) {
            float a = fabsf(u2f(u[2 * i]));
            if (a == 0.f || (a >= 9.765625e-4f && a <= 2.0f)) plausible++;
        }
        *flag = (plausible >= 40) ? 1 : 0;
    }
}

// ---------- atomic-free bucket partition (digit = dst>>7) ----------
__global__ __launch_bounds__(256) void k_bhist(const int* __restrict__ src,
                                               const int* __restrict__ dst,
                                               int* __restrict__ bhistT) {
    __shared__ int h[NBKT];
    int blk = blockIdx.x;
    for (int i = threadIdx.x; i < NBKT; i += 256) h[i] = 0;
    __syncthreads();
    int base = blk * TILE;
    for (int i = threadIdx.x; i < TILE; i += 256) {
        int e = base + i;
        if (e < N_EDGES) {
            int s = src[e], d = dst[e];
            if (s != d) atomicAdd(&h[d >> 7], 1);
        }
    }
    __syncthreads();
    for (int i = threadIdx.x; i < NBKT; i += 256) bhistT[i * NBKT_PAD + blk] = h[i];
}

__global__ __launch_bounds__(64) void k_bscan(int* __restrict__ bhistT,
                                              int* __restrict__ btot) {
    int b = blockIdx.x;
    int lane = threadIdx.x;
    int* row = &bhistT[b * NBKT_PAD];
    int carry = 0;
    for (int c = 0; c < NTILE; c += 64) {
        int idx = c + lane;
        int v = (idx < NTILE) ? row[idx] : 0;
        int sc = v;
#pragma unroll
        for (int off = 1; off < 64; off <<= 1) {
            int t = __shfl_up(sc, off);
            if (lane >= off) sc += t;
        }
        if (idx < NTILE) row[idx] = sc - v + carry;   // exclusive + carry
        carry += __shfl(sc, 63);
    }
    if (lane == 0) btot[b] = carry;
}

__global__ void k_btscan(const int* __restrict__ btot, int* __restrict__ bstart) {
    __shared__ int sh[1024];
    int v = ((int)threadIdx.x < NBKT) ? btot[threadIdx.x] : 0;
    sh[threadIdx.x] = v;
    __syncthreads();
    for (int off = 1; off < 1024; off <<= 1) {
        int t = (threadIdx.x >= off) ? sh[threadIdx.x - off] : 0;
        __syncthreads();
        sh[threadIdx.x] += t;
        __syncthreads();
    }
    if ((int)threadIdx.x < NBKT) bstart[threadIdx.x] = sh[threadIdx.x] - v;
    if (threadIdx.x == NBKT - 1) bstart[NBKT] = sh[threadIdx.x];
}

__global__ __launch_bounds__(256) void k_bscatter(const int* __restrict__ src,
                                                  const int* __restrict__ dst,
                                                  const int* __restrict__ bhistT,
                                                  const int* __restrict__ bstart,
                                                  int2* __restrict__ ebuf) {
    __shared__ int cur[NBKT];
    int blk = blockIdx.x;
    for (int i = threadIdx.x; i < NBKT; i += 256)
        cur[i] = bstart[i] + bhistT[i * NBKT_PAD + blk];
    __syncthreads();
    int base = blk * TILE;
    for (int i = threadIdx.x; i < TILE; i += 256) {
        int e = base + i;
        if (e < N_EDGES) {
            int s = src[e], d = dst[e];
            if (s != d) {
                int p = atomicAdd(&cur[d >> 7], 1);
                ebuf[p] = make_int2(s, d);
            }
        }
    }
}

__global__ __launch_bounds__(256) void k_bcsr(const int2* __restrict__ ebuf,
                                              const int* __restrict__ bstart,
                                              int* __restrict__ rs,
                                              float* __restrict__ dis,
                                              int* __restrict__ csr) {
    __shared__ int dloc[128];
    __shared__ int sc[128];
    int b = blockIdx.x;
    int node0 = b << 7;
    int nn = N_NODES - node0; if (nn > 128) nn = 128;
    int tid = threadIdx.x;
    if (tid < 128) dloc[tid] = 0;
    __syncthreads();
    int s = bstart[b], e = bstart[b + 1];
    for (int i = s + tid; i < e; i += 256)
        atomicAdd(&dloc[ebuf[i].y - node0], 1);
    __syncthreads();
    if (tid < 128) sc[tid] = dloc[tid];
    __syncthreads();
    for (int off = 1; off < 128; off <<= 1) {
        int t = (tid >= off && tid < 128) ? sc[tid - off] : 0;
        __syncthreads();
        if (tid < 128) sc[tid] += t;
        __syncthreads();
    }
    if (tid < nn) {
        rs[node0 + tid] = s + sc[tid] - dloc[tid];
        dis[node0 + tid] = rsqrtf((float)dloc[tid] + 1.0f);
    }
    if (b == NBKT - 1 && tid == 0) rs[N_NODES] = e;
    __syncthreads();
    if (tid < 128) dloc[tid] = s + sc[tid] - dloc[tid];  // cursors
    __syncthreads();
    for (int i = s + tid; i < e; i += 256) {
        int2 p = ebuf[i];
        int pos = atomicAdd(&dloc[p.y - node0], 1);
        csr[pos] = p.x;
    }
}

__global__ void k_gstart(const int* __restrict__ batch, int* __restrict__ gstart) {
    int g = blockIdx.x * 256 + threadIdx.x;
    if (g > NGRAPH) return;
    int lo = 0, hi = N_NODES;
    while (lo < hi) {
        int mid = (lo + hi) >> 1;
        if (batch[mid] < g) lo = mid + 1; else hi = mid;
    }
    gstart[g] = lo;
}

// ---------- GCN layers (activations f32; ts = dis * (x @ W)) ----------
__global__ __launch_bounds__(256) void k_mm1(const void* __restrict__ x,
                                             const void* __restrict__ w,
                                             const int* __restrict__ flagp,
                                             const float* __restrict__ dis,
                                             float* __restrict__ ts) {
    __shared__ float Wl[128 * 32];
    __shared__ float Xs[32][128];
    int bf = *flagp;
    int tid = threadIdx.x;
    int nbase = blockIdx.x * 32;          // N_NODES % 32 == 0: always full
    if (bf) {
        const ushort4* wv = (const ushort4*)w;
        for (int idx = tid; idx < 1024; idx += 256) {
            ushort4 h = wv[idx];
            int p = idx * 4;
            Wl[p] = u2f(h.x); Wl[p + 1] = u2f(h.y); Wl[p + 2] = u2f(h.z); Wl[p + 3] = u2f(h.w);
        }
        const ushort4* xv = (const ushort4*)x;
        for (int idx = tid; idx < 1024; idx += 256) {
            int nd = idx >> 5, q = idx & 31;
            ushort4 h = xv[(size_t)(nbase + nd) * 32 + q];
            float* d = &Xs[nd][q * 4];
            d[0] = u2f(h.x); d[1] = u2f(h.y); d[2] = u2f(h.z); d[3] = u2f(h.w);
        }
    } else {
        const float* wf = (const float*)w;
        for (int idx = tid; idx < 4096; idx += 256) Wl[idx] = wf[idx];
        const float* xf = (const float*)x;
        for (int idx = tid; idx < 4096; idx += 256)
            Xs[idx >> 7][idx & 127] = xf[(size_t)nbase * 128 + idx];
    }
    __syncthreads();
    int grp = tid >> 5, col = tid & 31;
    for (int rep = 0; rep < 4; rep++) {
        int sub = grp + 8 * rep;
        int node = nbase + sub;
        float acc = 0.f;
#pragma unroll 8
        for (int k = 0; k < 128; k++) acc += Xs[sub][k] * Wl[k * 32 + col];
        ts[node * 32 + col] = dis[node] * acc;
    }
}

__global__ __launch_bounds__(256) void k_mm32(const float* __restrict__ xin,
                                              const void* __restrict__ w,
                                              const int* __restrict__ flagp,
                                              const float* __restrict__ dis,
                                              float* __restrict__ ts) {
    __shared__ float Wl[32 * 32];
    __shared__ float Xs[32][32];
    int bf = *flagp;
    int tid = threadIdx.x;
    int nbase = blockIdx.x * 32;
    if (bf) {
        const ushort4* wv = (const ushort4*)w;
        for (int idx = tid; idx < 256; idx += 256) {
            ushort4 h = wv[idx];
            int p = idx * 4;
            Wl[p] = u2f(h.x); Wl[p + 1] = u2f(h.y); Wl[p + 2] = u2f(h.z); Wl[p + 3] = u2f(h.w);
        }
    } else {
        const float* wf = (const float*)w;
        for (int idx = tid; idx < 1024; idx += 256) Wl[idx] = wf[idx];
    }
    {
        const float4* xv = (const float4*)xin;
        int nd = tid >> 3, q = tid & 7;
        float4 v = xv[(size_t)(nbase + nd) * 8 + q];
        float* d = &Xs[nd][q * 4];
        d[0] = v.x; d[1] = v.y; d[2] = v.z; d[3] = v.w;
    }
    __syncthreads();
    int grp = tid >> 5, col = tid & 31;
    for (int rep = 0; rep < 4; rep++) {
        int sub = grp + 8 * rep;
        int node = nbase + sub;
        float acc = 0.f;
#pragma unroll
        for (int k = 0; k < 32; k++) acc += Xs[sub][k] * Wl[k * 32 + col];
        ts[node * 32 + col] = dis[node] * acc;
    }
}

__global__ __launch_bounds__(256) void k_mm_out1(const float* __restrict__ xin,
                                                 const void* __restrict__ w4,
                                                 const int* __restrict__ flagp,
                                                 const float* __restrict__ dis,
                                                 float* __restrict__ ts4) {
    int node = blockIdx.x * 8 + (threadIdx.x >> 5);
    int lane = threadIdx.x & 31;
    if (node >= N_NODES) return;
    int bf = *flagp;
    float v = xin[node * 32 + lane] * LD(w4, lane, bf);
    for (int off = 16; off; off >>= 1) v += __shfl_down(v, off, 32);
    if (lane == 0) ts4[node] = dis[node] * v;
}

// One wave64 per node; 8 lanes per row (float4/lane); gather loop unrolled x4
// => up to 32 neighbor rows in flight per wave.
__global__ __launch_bounds__(256) void k_agg32(const float4* __restrict__ ts,
                                               const int* __restrict__ rs,
                                               const int* __restrict__ csr,
                                               const float* __restrict__ dis,
                                               const void* __restrict__ b,
                                               const int* __restrict__ flagp,
                                               float4* __restrict__ out) {
    int node = blockIdx.x * 4 + (threadIdx.x >> 6);
    int lane = threadIdx.x & 63;
    int q   = lane & 7;
    int grp = lane >> 3;
    int bf = *flagp;
    int s = rs[node], e = rs[node + 1];
    float4 a0 = make_float4(0.f, 0.f, 0.f, 0.f);
    float4 a1 = a0, a2 = a0, a3 = a0;
    int i = s + grp;
    for (; i + 24 < e; i += 32) {
        int v0 = csr[i], v1 = csr[i + 8], v2 = csr[i + 16], v3 = csr[i + 24];
        float4 m0 = ts[v0 * 8 + q];
        float4 m1 = ts[v1 * 8 + q];
        float4 m2 = ts[v2 * 8 + q];
        float4 m3 = ts[v3 * 8 + q];
        a0.x += m0.x; a0.y += m0.y; a0.z += m0.z; a0.w += m0.w;
        a1.x += m1.x; a1.y += m1.y; a1.z += m1.z; a1.w += m1.w;
        a2.x += m2.x; a2.y += m2.y; a2.z += m2.z; a2.w += m2.w;
        a3.x += m3.x; a3.y += m3.y; a3.z += m3.z; a3.w += m3.w;
    }
    for (; i < e; i += 8) {
        float4 m = ts[csr[i] * 8 + q];
        a0.x += m.x; a0.y += m.y; a0.z += m.z; a0.w += m.w;
    }
    float4 acc;
    acc.x = (a0.x + a1.x) + (a2.x + a3.x);
    acc.y = (a0.y + a1.y) + (a2.y + a3.y);
    acc.z = (a0.z + a1.z) + (a2.z + a3.z);
    acc.w = (a0.w + a1.w) + (a2.w + a3.w);
#pragma unroll
    for (int off = 8; off < 64; off <<= 1) {
        acc.x += __shfl_xor(acc.x, off);
        acc.y += __shfl_xor(acc.y, off);
        acc.z += __shfl_xor(acc.z, off);
        acc.w += __shfl_xor(acc.w, off);
    }
    if (grp == 0) {
        float4 self = ts[node * 8 + q];
        float d = dis[node];
        float4 r;
        r.x = tanhf(d * (acc.x + self.x) + LD(b, q * 4 + 0, bf));
        r.y = tanhf(d * (acc.y + self.y) + LD(b, q * 4 + 1, bf));
        r.z = tanhf(d * (acc.z + self.z) + LD(b, q * 4 + 2, bf));
        r.w = tanhf(d * (acc.w + self.w) + LD(b, q * 4 + 3, bf));
        out[node * 8 + q] = r;
    }
}

// 16 lanes per node.
__global__ __launch_bounds__(256) void k_agg1(const float* __restrict__ ts4,
                                              const int* __restrict__ rs,
                                              const int* __restrict__ csr,
                                              const float* __restrict__ dis,
                                              const void* __restrict__ b4,
                                              const int* __restrict__ flagp,
                                              float* __restrict__ x4) {
    int node = blockIdx.x * 16 + (threadIdx.x >> 4);
    int lane = threadIdx.x & 15;
    int s = rs[node], e = rs[node + 1];
    float acc = 0.f;
    for (int i = s + lane; i < e; i += 16) acc += ts4[csr[i]];
#pragma unroll
    for (int off = 1; off < 16; off <<= 1) acc += __shfl_xor(acc, off);
    if (lane == 0) {
        int bf = *flagp;
        x4[node] = tanhf(dis[node] * (acc + ts4[node]) + LD(b4, 0, bf));
    }
}

// ---------- SortPooling rank ----------
__global__ __launch_bounds__(256) void k_rank(const int* __restrict__ batch,
                                              const int* __restrict__ gstart,
                                              const float* __restrict__ x4,
                                              int* __restrict__ sel) {
    int i = blockIdx.x * 256 + threadIdx.x;
    if (i >= N_NODES) return;
    int g = batch[i];
    int s = gstart[g], e = gstart[g + 1];
    float ki = x4[i];
    int rank = 0;
    for (int j = s; j < e; j++) {
        float kj = x4[j];
        rank += (kj > ki) || (kj == ki && j < i);
    }
    if (rank < KTOP) sel[g * KTOP + rank] = i;
}

// ---------- Pooled-tensor gather ----------
__global__ __launch_bounds__(256) void k_pool(const float* __restrict__ x1,
                                              const float* __restrict__ x2,
                                              const float* __restrict__ x3,
                                              const float* __restrict__ x4,
                                              const int* __restrict__ sel,
                                              float* __restrict__ P) {
    int idx = blockIdx.x * 256 + threadIdx.x;
    if (idx >= PELEM) return;
    int g = idx / (KTOP * 97);
    int r = idx - g * (KTOP * 97);
    int p = r / 97;
    int f = r - p * 97;
    int v = sel[g * KTOP + p];
    float val = 0.f;
    if (v >= 0) {
        if (f < 32)      val = x1[v * 32 + f];
        else if (f < 64) val = x2[v * 32 + f - 32];
        else if (f < 96) val = x3[v * 32 + f - 64];
        else             val = x4[v];
    }
    P[idx] = val;
}

// ---------- CNN/MLP head: 256 threads/graph, 4-way ILP on all chains ----------
__global__ __launch_bounds__(256) void k_head(
    const float* __restrict__ Pg,
    const void* __restrict__ w5, const void* __restrict__ b5,
    const void* __restrict__ w6, const void* __restrict__ b6,
    const void* __restrict__ f1w, const void* __restrict__ f1b,
    const void* __restrict__ f2w, const void* __restrict__ f2b,
    const int* __restrict__ flagp, void* __restrict__ out) {
    __shared__ float P[KTOP * 97];
    __shared__ float W5[16 * 97];
    __shared__ float W6[32 * 16 * 5];
    __shared__ float H5[16][30];
    __shared__ float M[16][15];
    __shared__ float H6[352];
    __shared__ float Rp[2][128];
    __shared__ float R1[128];
    __shared__ float L[10];
    __shared__ float mls;
    int g = blockIdx.x;
    int tid = threadIdx.x;
    int bf = *flagp;

    for (int i = tid; i < KTOP * 97; i += 256) P[i] = Pg[g * (KTOP * 97) + i];
    for (int i = tid; i < 16 * 97; i += 256) W5[i] = LD(w5, i, bf);
    for (int i = tid; i < 2560; i += 256) W6[i] = LD(w6, i, bf);
    __syncthreads();
    for (int idx = tid; idx < 480; idx += 256) {   // conv5 + relu (4-acc ILP)
        int o = idx / 30, p = idx - o * 30;
        const float* pr = &P[p * 97];
        const float* wr = &W5[o * 97];
        float a0 = 0.f, a1 = 0.f, a2 = 0.f, a3 = 0.f;
        for (int f = 0; f < 96; f += 4) {
            a0 += wr[f] * pr[f];
            a1 += wr[f + 1] * pr[f + 1];
            a2 += wr[f + 2] * pr[f + 2];
            a3 += wr[f + 3] * pr[f + 3];
        }
        float acc = LD(b5, o, bf) + ((a0 + a1) + (a2 + a3)) + wr[96] * pr[96];
        H5[o][p] = fmaxf(acc, 0.f);
    }
    __syncthreads();
    for (int idx = tid; idx < 240; idx += 256) {   // maxpool2
        int o = idx / 15, q = idx - o * 15;
        M[o][q] = fmaxf(H5[o][2 * q], H5[o][2 * q + 1]);
    }
    __syncthreads();
    for (int idx = tid; idx < 352; idx += 256) {   // conv6 + relu
        int oc = idx / 11, tp = idx - oc * 11;
        float acc = LD(b6, oc, bf);
        const float* wr = &W6[oc * 80];
        for (int ic = 0; ic < 16; ic++) {
#pragma unroll
            for (int k = 0; k < 5; k++)
                acc += wr[ic * 5 + k] * M[ic][tp + k];
        }
        H6[idx] = fmaxf(acc, 0.f);
    }
    __syncthreads();
    {   // fc1: 2 threads per output column, 176 terms each, 4-acc ILP
        int half = tid >> 7, col = tid & 127;
        int base = half * 176;
        float a0 = 0.f, a1 = 0.f, a2 = 0.f, a3 = 0.f;
        for (int i = 0; i < 176; i += 4) {
            int ii = base + i;
            a0 += H6[ii] * LD(f1w, ii * 128 + col, bf);
            a1 += H6[ii + 1] * LD(f1w, (ii + 1) * 128 + col, bf);
            a2 += H6[ii + 2] * LD(f1w, (ii + 2) * 128 + col, bf);
            a3 += H6[ii + 3] * LD(f1w, (ii + 3) * 128 + col, bf);
        }
        Rp[half][col] = (a0 + a1) + (a2 + a3);
    }
    __syncthreads();
    if (tid < 128) R1[tid] = fmaxf(LD(f1b, tid, bf) + Rp[0][tid] + Rp[1][tid], 0.f);
    __syncthreads();
    if (tid < 10) {   // fc2 (4-acc ILP)
        float a0 = 0.f, a1 = 0.f, a2 = 0.f, a3 = 0.f;
        for (int k = 0; k < 128; k += 4) {
            a0 += R1[k] * LD(f2w, k * 10 + tid, bf);
            a1 += R1[k + 1] * LD(f2w, (k + 1) * 10 + tid, bf);
            a2 += R1[k + 2] * LD(f2w, (k + 2) * 10 + tid, bf);
            a3 += R1[k + 3] * LD(f2w, (k + 3) * 10 + tid, bf);
        }
        L[tid] = LD(f2b, tid, bf) + ((a0 + a1) + (a2 + a3));
    }
    __syncthreads();
    if (tid == 0) {
        float m = L[0];
        for (int c = 1; c < 10; c++) m = fmaxf(m, L[c]);
        float ssum = 0.f;
        for (int c = 0; c < 10; c++) ssum += expf(L[c] - m);
        mls = m + logf(ssum);
    }
    __syncthreads();
    if (tid < 10) {
        float v = L[tid] - mls;
        if (bf) ((bf16*)out)[g * 10 + tid] = __float2bfloat16(v);
        else    ((float*)out)[g * 10 + tid] = v;
    }
}

extern "C" void kernel_launch(void* const* d_in, const int* in_sizes, int n_in,
                              void* d_out, int out_size, void* d_ws, size_t ws_size,
                              hipStream_t stream) {
    const void* x   = d_in[0];
    const void* w1  = d_in[1];  const void* b1  = d_in[2];
    const void* w2  = d_in[3];  const void* b2  = d_in[4];
    const void* w3  = d_in[5];  const void* b3  = d_in[6];
    const void* w4  = d_in[7];  const void* b4  = d_in[8];
    const void* w5  = d_in[9];  const void* b5  = d_in[10];
    const void* w6  = d_in[11]; const void* b6  = d_in[12];
    const void* f1w = d_in[13]; const void* f1b = d_in[14];
    const void* f2w = d_in[15]; const void* f2b = d_in[16];
    const int* esrc  = (const int*)d_in[17];
    const int* edst  = (const int*)d_in[18];
    const int* batch = (const int*)d_in[19];

    char* w = (char*)d_ws;
    size_t off = 0;
    auto alloc = [&](size_t bytes) {
        void* p = w + off;
        off += (bytes + 255) & ~(size_t)255;
        return p;
    };
    int*   flag   = (int*)  alloc(256);
    int*   rs     = (int*)  alloc((size_t)(N_NODES + 1) * 4);
    float* dis    = (float*)alloc((size_t)N_NODES * 4);
    int*   csr    = (int*)  alloc((size_t)N_EDGES * 4);
    float* t      = (float*)alloc((size_t)N_NODES * 32 * 4);   // aliased by ebuf (1st half)
    float* x1     = (float*)alloc((size_t)N_NODES * 32 * 4);   // aliased by ebuf (2nd half)
    float* x2     = (float*)alloc((size_t)N_NODES * 32 * 4);
    float* x3     = (float*)alloc((size_t)N_NODES * 32 * 4);
    float* x4     = (float*)alloc((size_t)N_NODES * 4);
    int*   gstart = (int*)  alloc((size_t)(NGRAPH + 1) * 4);
    int*   sel    = (int*)  alloc((size_t)NGRAPH * KTOP * 4);
    float* Pg     = (float*)alloc((size_t)PELEM * 4);
    int*   bhistT = (int*)  alloc((size_t)NBKT * NBKT_PAD * 4);
    int*   btot   = (int*)  alloc((size_t)NBKT * 4);
    int*   bstart = (int*)  alloc((size_t)(NBKT + 1) * 4);
    (void)ws_size; (void)n_in; (void)in_sizes; (void)out_size;

    int2* ebuf = (int2*)t;   // dead until k_mm1

    hipMemsetAsync(sel, 0xFF, (size_t)NGRAPH * KTOP * 4, stream);

    int nb   = (N_NODES + 255) / 256;
    int mb32 = N_NODES / 32;
    int ab   = N_NODES / 4;
    int a1b  = N_NODES / 16;
    int pb   = (PELEM + 255) / 256;

    k_detect<<<1, 64, 0, stream>>>(w1, flag);
    k_bhist<<<NTILE, 256, 0, stream>>>(esrc, edst, bhistT);
    k_bscan<<<NBKT, 64, 0, stream>>>(bhistT, btot);
    k_btscan<<<1, 1024, 0, stream>>>(btot, bstart);
    k_bscatter<<<NTILE, 256, 0, stream>>>(esrc, edst, bhistT, bstart, ebuf);
    k_bcsr<<<NBKT, 256, 0, stream>>>(ebuf, bstart, rs, dis, csr);
    k_gstart<<<5, 256, 0, stream>>>(batch, gstart);

    k_mm1<<<mb32, 256, 0, stream>>>(x, w1, flag, dis, t);
    k_agg32<<<ab, 256, 0, stream>>>((const float4*)t, rs, csr, dis, b1, flag, (float4*)x1);
    k_mm32<<<mb32, 256, 0, stream>>>(x1, w2, flag, dis, t);
    k_agg32<<<ab, 256, 0, stream>>>((const float4*)t, rs, csr, dis, b2, flag, (float4*)x2);
    k_mm32<<<mb32, 256, 0, stream>>>(x2, w3, flag, dis, t);
    k_agg32<<<ab, 256, 0, stream>>>((const float4*)t, rs, csr, dis, b3, flag, (float4*)x3);
    k_mm_out1<<<(N_NODES + 7) / 8, 256, 0, stream>>>(x3, w4, flag, dis, t);
    k_agg1<<<a1b, 256, 0, stream>>>(t, rs, csr, dis, b4, flag, x4);
    k_rank<<<nb, 256, 0, stream>>>(batch, gstart, x4, sel);
    k_pool<<<pb, 256, 0, stream>>>(x1, x2, x3, x4, sel, Pg);
    k_head<<<NGRAPH, 256, 0, stream>>>(Pg, w5, b5, w6, b6,
                                       f1w, f1b, f2w, f2b, flag, (void*)d_out);
}

// Round 10
// 642.799 us; speedup vs baseline: 1.0654x; 1.0654x over previous
//
#include <hip/hip_runtime.h>
#include <hip/hip_bf16.h>

#define N_NODES 100000
#define N_EDGES 3200000
#define NGRAPH 1024
#define KTOP 30
#define PELEM (NGRAPH * KTOP * 97)         // pooled tensor elements

#define NBKT 782                            // ceil(100000 / 128) node buckets
#define NBKT_PAD 392                        // padded tile-count row (>= NTILE)
#define NTILE 391                           // edge tiles
#define TILE 8192                           // edges per tile (391*8192 >= 3.2M)

typedef __hip_bfloat16 bf16;

__device__ __forceinline__ float u2f(unsigned short h) {
    return __uint_as_float(((unsigned int)h) << 16);
}
// Flag-steered scalar load of a float-tensor input that may be bf16 or f32.
__device__ __forceinline__ float LD(const void* p, int i, int bf) {
    if (bf) return u2f(((const unsigned short*)p)[i]);
    return ((const float*)p)[i];
}

// ---------- dtype probe ----------
__global__ void k_detect(const void* w1, int* flag) {
    if (threadIdx.x == 0 && blockIdx.x == 0) {
        const unsigned short* u = (const unsigned short*)w1;
        int plausible = 0;
        for (int i = 0; i < 64; i++) {
            float a = fabsf(u2f(u[2 * i]));
            if (a == 0.f || (a >= 9.765625e-4f && a <= 2.0f)) plausible++;
        }
        *flag = (plausible >= 40) ? 1 : 0;
    }
}

// ---------- atomic-free bucket partition (digit = dst>>7) ----------
__global__ __launch_bounds__(256) void k_bhist(const int* __restrict__ src,
                                               const int* __restrict__ dst,
                                               int* __restrict__ bhistT) {
    __shared__ int h[NBKT];
    int blk = blockIdx.x;
    for (int i = threadIdx.x; i < NBKT; i += 256) h[i] = 0;
    __syncthreads();
    int base = blk * TILE;
    for (int i = threadIdx.x; i < TILE; i += 256) {
        int e = base + i;
        if (e < N_EDGES) {
            int s = src[e], d = dst[e];
            if (s != d) atomicAdd(&h[d >> 7], 1);
        }
    }
    __syncthreads();
    for (int i = threadIdx.x; i < NBKT; i += 256) bhistT[i * NBKT_PAD + blk] = h[i];
}

__global__ __launch_bounds__(64) void k_bscan(int* __restrict__ bhistT,
                                              int* __restrict__ btot) {
    int b = blockIdx.x;
    int lane = threadIdx.x;
    int* row = &bhistT[b * NBKT_PAD];
    int carry = 0;
    for (int c = 0; c < NTILE; c += 64) {
        int idx = c + lane;
        int v = (idx < NTILE) ? row[idx] : 0;
        int sc = v;
#pragma unroll
        for (int off = 1; off < 64; off <<= 1) {
            int t = __shfl_up(sc, off);
            if (lane >= off) sc += t;
        }
        if (idx < NTILE) row[idx] = sc - v + carry;   // exclusive + carry
        carry += __shfl(sc, 63);
    }
    if (lane == 0) btot[b] = carry;
}

__global__ void k_btscan(const int* __restrict__ btot, int* __restrict__ bstart) {
    __shared__ int sh[1024];
    int v = ((int)threadIdx.x < NBKT) ? btot[threadIdx.x] : 0;
    sh[threadIdx.x] = v;
    __syncthreads();
    for (int off = 1; off < 1024; off <<= 1) {
        int t = (threadIdx.x >= off) ? sh[threadIdx.x - off] : 0;
        __syncthreads();
        sh[threadIdx.x] += t;
        __syncthreads();
    }
    if ((int)threadIdx.x < NBKT) bstart[threadIdx.x] = sh[threadIdx.x] - v;
    if (threadIdx.x == NBKT - 1) bstart[NBKT] = sh[threadIdx.x];
}

__global__ __launch_bounds__(256) void k_bscatter(const int* __restrict__ src,
                                                  const int* __restrict__ dst,
                                                  const int* __restrict__ bhistT,
                                                  const int* __restrict__ bstart,
                                                  int2* __restrict__ ebuf) {
    __shared__ int cur[NBKT];
    int blk = blockIdx.x;
    for (int i = threadIdx.x; i < NBKT; i += 256)
        cur[i] = bstart[i] + bhistT[i * NBKT_PAD + blk];
    __syncthreads();
    int base = blk * TILE;
    for (int i = threadIdx.x; i < TILE; i += 256) {
        int e = base + i;
        if (e < N_EDGES) {
            int s = src[e], d = dst[e];
            if (s != d) {
                int p = atomicAdd(&cur[d >> 7], 1);
                ebuf[p] = make_int2(s, d);
            }
        }
    }
}

__global__ __launch_bounds__(256) void k_bcsr(const int2* __restrict__ ebuf,
                                              const int* __restrict__ bstart,
                                              int* __restrict__ rs,
                                              float* __restrict__ dis,
                                              int* __restrict__ csr) {
    __shared__ int dloc[128];
    __shared__ int sc[128];
    int b = blockIdx.x;
    int node0 = b << 7;
    int nn = N_NODES - node0; if (nn > 128) nn = 128;
    int tid = threadIdx.x;
    if (tid < 128) dloc[tid] = 0;
    __syncthreads();
    int s = bstart[b], e = bstart[b + 1];
    for (int i = s + tid; i < e; i += 256)
        atomicAdd(&dloc[ebuf[i].y - node0], 1);
    __syncthreads();
    if (tid < 128) sc[tid] = dloc[tid];
    __syncthreads();
    for (int off = 1; off < 128; off <<= 1) {
        int t = (tid >= off && tid < 128) ? sc[tid - off] : 0;
        __syncthreads();
        if (tid < 128) sc[tid] += t;
        __syncthreads();
    }
    if (tid < nn) {
        rs[node0 + tid] = s + sc[tid] - dloc[tid];
        dis[node0 + tid] = rsqrtf((float)dloc[tid] + 1.0f);
    }
    if (b == NBKT - 1 && tid == 0) rs[N_NODES] = e;
    __syncthreads();
    if (tid < 128) dloc[tid] = s + sc[tid] - dloc[tid];  // cursors
    __syncthreads();
    for (int i = s + tid; i < e; i += 256) {
        int2 p = ebuf[i];
        int pos = atomicAdd(&dloc[p.y - node0], 1);
        csr[pos] = p.x;
    }
}

__global__ void k_gstart(const int* __restrict__ batch, int* __restrict__ gstart) {
    int g = blockIdx.x * 256 + threadIdx.x;
    if (g > NGRAPH) return;
    int lo = 0, hi = N_NODES;
    while (lo < hi) {
        int mid = (lo + hi) >> 1;
        if (batch[mid] < g) lo = mid + 1; else hi = mid;
    }
    gstart[g] = lo;
}

// ---------- GCN layers (activations f32; ts = dis * (x @ W)) ----------
__global__ __launch_bounds__(256) void k_mm1(const void* __restrict__ x,
                                             const void* __restrict__ w,
                                             const int* __restrict__ flagp,
                                             const float* __restrict__ dis,
                                             float* __restrict__ ts) {
    __shared__ float Wl[128 * 32];
    __shared__ float Xs[32][128];
    int bf = *flagp;
    int tid = threadIdx.x;
    int nbase = blockIdx.x * 32;          // N_NODES % 32 == 0: always full
    if (bf) {
        const ushort4* wv = (const ushort4*)w;
        for (int idx = tid; idx < 1024; idx += 256) {
            ushort4 h = wv[idx];
            int p = idx * 4;
            Wl[p] = u2f(h.x); Wl[p + 1] = u2f(h.y); Wl[p + 2] = u2f(h.z); Wl[p + 3] = u2f(h.w);
        }
        const ushort4* xv = (const ushort4*)x;
        for (int idx = tid; idx < 1024; idx += 256) {
            int nd = idx >> 5, q = idx & 31;
            ushort4 h = xv[(size_t)(nbase + nd) * 32 + q];
            float* d = &Xs[nd][q * 4];
            d[0] = u2f(h.x); d[1] = u2f(h.y); d[2] = u2f(h.z); d[3] = u2f(h.w);
        }
    } else {
        const float* wf = (const float*)w;
        for (int idx = tid; idx < 4096; idx += 256) Wl[idx] = wf[idx];
        const float* xf = (const float*)x;
        for (int idx = tid; idx < 4096; idx += 256)
            Xs[idx >> 7][idx & 127] = xf[(size_t)nbase * 128 + idx];
    }
    __syncthreads();
    int grp = tid >> 5, col = tid & 31;
    for (int rep = 0; rep < 4; rep++) {
        int sub = grp + 8 * rep;
        int node = nbase + sub;
        float acc = 0.f;
#pragma unroll 8
        for (int k = 0; k < 128; k++) acc += Xs[sub][k] * Wl[k * 32 + col];
        ts[node * 32 + col] = dis[node] * acc;
    }
}

__global__ __launch_bounds__(256) void k_mm32(const float* __restrict__ xin,
                                              const void* __restrict__ w,
                                              const int* __restrict__ flagp,
                                              const float* __restrict__ dis,
                                              float* __restrict__ ts) {
    __shared__ float Wl[32 * 32];
    __shared__ float Xs[32][32];
    int bf = *flagp;
    int tid = threadIdx.x;
    int nbase = blockIdx.x * 32;
    if (bf) {
        const ushort4* wv = (const ushort4*)w;
        for (int idx = tid; idx < 256; idx += 256) {
            ushort4 h = wv[idx];
            int p = idx * 4;
            Wl[p] = u2f(h.x); Wl[p + 1] = u2f(h.y); Wl[p + 2] = u2f(h.z); Wl[p + 3] = u2f(h.w);
        }
    } else {
        const float* wf = (const float*)w;
        for (int idx = tid; idx < 1024; idx += 256) Wl[idx] = wf[idx];
    }
    {
        const float4* xv = (const float4*)xin;
        int nd = tid >> 3, q = tid & 7;
        float4 v = xv[(size_t)(nbase + nd) * 8 + q];
        float* d = &Xs[nd][q * 4];
        d[0] = v.x; d[1] = v.y; d[2] = v.z; d[3] = v.w;
    }
    __syncthreads();
    int grp = tid >> 5, col = tid & 31;
    for (int rep = 0; rep < 4; rep++) {
        int sub = grp + 8 * rep;
        int node = nbase + sub;
        float acc = 0.f;
#pragma unroll
        for (int k = 0; k < 32; k++) acc += Xs[sub][k] * Wl[k * 32 + col];
        ts[node * 32 + col] = dis[node] * acc;
    }
}

__global__ __launch_bounds__(256) void k_mm_out1(const float* __restrict__ xin,
                                                 const void* __restrict__ w4,
                                                 const int* __restrict__ flagp,
                                                 const float* __restrict__ dis,
                                                 float* __restrict__ ts4) {
    int node = blockIdx.x * 8 + (threadIdx.x >> 5);
    int lane = threadIdx.x & 31;
    if (node >= N_NODES) return;
    int bf = *flagp;
    float v = xin[node * 32 + lane] * LD(w4, lane, bf);
    for (int off = 16; off; off >>= 1) v += __shfl_down(v, off, 32);
    if (lane == 0) ts4[node] = dis[node] * v;
}

// One wave64 per node; 8 lanes per row (float4/lane); gather loop unrolled x4
// => up to 32 neighbor rows in flight per wave.
__global__ __launch_bounds__(256) void k_agg32(const float4* __restrict__ ts,
                                               const int* __restrict__ rs,
                                               const int* __restrict__ csr,
                                               const float* __restrict__ dis,
                                               const void* __restrict__ b,
                                               const int* __restrict__ flagp,
                                               float4* __restrict__ out) {
    int node = blockIdx.x * 4 + (threadIdx.x >> 6);
    int lane = threadIdx.x & 63;
    int q   = lane & 7;
    int grp = lane >> 3;
    int bf = *flagp;
    int s = rs[node], e = rs[node + 1];
    float4 a0 = make_float4(0.f, 0.f, 0.f, 0.f);
    float4 a1 = a0, a2 = a0, a3 = a0;
    int i = s + grp;
    for (; i + 24 < e; i += 32) {
        int v0 = csr[i], v1 = csr[i + 8], v2 = csr[i + 16], v3 = csr[i + 24];
        float4 m0 = ts[v0 * 8 + q];
        float4 m1 = ts[v1 * 8 + q];
        float4 m2 = ts[v2 * 8 + q];
        float4 m3 = ts[v3 * 8 + q];
        a0.x += m0.x; a0.y += m0.y; a0.z += m0.z; a0.w += m0.w;
        a1.x += m1.x; a1.y += m1.y; a1.z += m1.z; a1.w += m1.w;
        a2.x += m2.x; a2.y += m2.y; a2.z += m2.z; a2.w += m2.w;
        a3.x += m3.x; a3.y += m3.y; a3.z += m3.z; a3.w += m3.w;
    }
    for (; i < e; i += 8) {
        float4 m = ts[csr[i] * 8 + q];
        a0.x += m.x; a0.y += m.y; a0.z += m.z; a0.w += m.w;
    }
    float4 acc;
    acc.x = (a0.x + a1.x) + (a2.x + a3.x);
    acc.y = (a0.y + a1.y) + (a2.y + a3.y);
    acc.z = (a0.z + a1.z) + (a2.z + a3.z);
    acc.w = (a0.w + a1.w) + (a2.w + a3.w);
#pragma unroll
    for (int off = 8; off < 64; off <<= 1) {
        acc.x += __shfl_xor(acc.x, off);
        acc.y += __shfl_xor(acc.y, off);
        acc.z += __shfl_xor(acc.z, off);
        acc.w += __shfl_xor(acc.w, off);
    }
    if (grp == 0) {
        float4 self = ts[node * 8 + q];
        float d = dis[node];
        float4 r;
        r.x = tanhf(d * (acc.x + self.x) + LD(b, q * 4 + 0, bf));
        r.y = tanhf(d * (acc.y + self.y) + LD(b, q * 4 + 1, bf));
        r.z = tanhf(d * (acc.z + self.z) + LD(b, q * 4 + 2, bf));
        r.w = tanhf(d * (acc.w + self.w) + LD(b, q * 4 + 3, bf));
        out[node * 8 + q] = r;
    }
}

// 16 lanes per node.
__global__ __launch_bounds__(256) void k_agg1(const float* __restrict__ ts4,
                                              const int* __restrict__ rs,
                                              const int* __restrict__ csr,
                                              const float* __restrict__ dis,
                                              const void* __restrict__ b4,
                                              const int* __restrict__ flagp,
                                              float* __restrict__ x4) {
    int node = blockIdx.x * 16 + (threadIdx.x >> 4);
    int lane = threadIdx.x & 15;
    int s = rs[node], e = rs[node + 1];
    float acc = 0.f;
    for (int i = s + lane; i < e; i += 16) acc += ts4[csr[i]];
#pragma unroll
    for (int off = 1; off < 16; off <<= 1) acc += __shfl_xor(acc, off);
    if (lane == 0) {
        int bf = *flagp;
        x4[node] = tanhf(dis[node] * (acc + ts4[node]) + LD(b4, 0, bf));
    }
}

// ---------- SortPooling rank ----------
__global__ __launch_bounds__(256) void k_rank(const int* __restrict__ batch,
                                              const int* __restrict__ gstart,
                                              const float* __restrict__ x4,
                                              int* __restrict__ sel) {
    int i = blockIdx.x * 256 + threadIdx.x;
    if (i >= N_NODES) return;
    int g = batch[i];
    int s = gstart[g], e = gstart[g + 1];
    float ki = x4[i];
    int rank = 0;
    for (int j = s; j < e; j++) {
        float kj = x4[j];
        rank += (kj > ki) || (kj == ki && j < i);
    }
    if (rank < KTOP) sel[g * KTOP + rank] = i;
}

// ---------- Pooled-tensor gather ----------
__global__ __launch_bounds__(256) void k_pool(const float* __restrict__ x1,
                                              const float* __restrict__ x2,
                                              const float* __restrict__ x3,
                                              const float* __restrict__ x4,
                                              const int* __restrict__ sel,
                                              float* __restrict__ P) {
    int idx = blockIdx.x * 256 + threadIdx.x;
    if (idx >= PELEM) return;
    int g = idx / (KTOP * 97);
    int r = idx - g * (KTOP * 97);
    int p = r / 97;
    int f = r - p * 97;
    int v = sel[g * KTOP + p];
    float val = 0.f;
    if (v >= 0) {
        if (f < 32)      val = x1[v * 32 + f];
        else if (f < 64) val = x2[v * 32 + f - 32];
        else if (f < 96) val = x3[v * 32 + f - 64];
        else             val = x4[v];
    }
    P[idx] = val;
}

// ---------- CNN/MLP head: coalesced P, weights staged in LDS (round-8 version:
// 128 threads, VGPR ~88 — 256-thread/4-ILP variant regressed: VGPR 132, occ 11%) ----------
__global__ __launch_bounds__(128) void k_head(
    const float* __restrict__ Pg,
    const void* __restrict__ w5, const void* __restrict__ b5,
    const void* __restrict__ w6, const void* __restrict__ b6,
    const void* __restrict__ f1w, const void* __restrict__ f1b,
    const void* __restrict__ f2w, const void* __restrict__ f2b,
    const int* __restrict__ flagp, void* __restrict__ out) {
    __shared__ float P[KTOP * 97];
    __shared__ float W5[16 * 97];
    __shared__ float W6[32 * 16 * 5];
    __shared__ float H5[16][30];
    __shared__ float M[16][15];
    __shared__ float H6[352];
    __shared__ float R1[128];
    __shared__ float L[10];
    __shared__ float mls;
    int g = blockIdx.x;
    int tid = threadIdx.x;
    int bf = *flagp;

    for (int i = tid; i < KTOP * 97; i += 128) P[i] = Pg[g * (KTOP * 97) + i];
    for (int i = tid; i < 16 * 97; i += 128) W5[i] = LD(w5, i, bf);
    for (int i = tid; i < 2560; i += 128) W6[i] = LD(w6, i, bf);
    __syncthreads();
    for (int idx = tid; idx < 480; idx += 128) {   // conv5 + relu
        int o = idx / 30, p = idx - o * 30;
        float acc = LD(b5, o, bf);
        const float* pr = &P[p * 97];
        const float* wr = &W5[o * 97];
        for (int f = 0; f < 97; f++) acc += wr[f] * pr[f];
        H5[o][p] = fmaxf(acc, 0.f);
    }
    __syncthreads();
    for (int idx = tid; idx < 240; idx += 128) {   // maxpool2
        int o = idx / 15, q = idx - o * 15;
        M[o][q] = fmaxf(H5[o][2 * q], H5[o][2 * q + 1]);
    }
    __syncthreads();
    for (int idx = tid; idx < 352; idx += 128) {   // conv6 + relu
        int oc = idx / 11, tp = idx - oc * 11;
        float acc = LD(b6, oc, bf);
        const float* wr = &W6[oc * 80];
        for (int ic = 0; ic < 16; ic++) {
#pragma unroll
            for (int k = 0; k < 5; k++)
                acc += wr[ic * 5 + k] * M[ic][tp + k];
        }
        H6[idx] = fmaxf(acc, 0.f);
    }
    __syncthreads();
    {   // fc1 + relu
        float acc = LD(f1b, tid, bf);
        for (int i = 0; i < 352; i++) acc += H6[i] * LD(f1w, i * 128 + tid, bf);
        R1[tid] = fmaxf(acc, 0.f);
    }
    __syncthreads();
    if (tid < 10) {   // fc2
        float acc = LD(f2b, tid, bf);
        for (int k = 0; k < 128; k++) acc += R1[k] * LD(f2w, k * 10 + tid, bf);
        L[tid] = acc;
    }
    __syncthreads();
    if (tid == 0) {
        float m = L[0];
        for (int c = 1; c < 10; c++) m = fmaxf(m, L[c]);
        float ssum = 0.f;
        for (int c = 0; c < 10; c++) ssum += expf(L[c] - m);
        mls = m + logf(ssum);
    }
    __syncthreads();
    if (tid < 10) {
        float v = L[tid] - mls;
        if (bf) ((bf16*)out)[g * 10 + tid] = __float2bfloat16(v);
        else    ((float*)out)[g * 10 + tid] = v;
    }
}

extern "C" void kernel_launch(void* const* d_in, const int* in_sizes, int n_in,
                              void* d_out, int out_size, void* d_ws, size_t ws_size,
                              hipStream_t stream) {
    const void* x   = d_in[0];
    const void* w1  = d_in[1];  const void* b1  = d_in[2];
    const void* w2  = d_in[3];  const void* b2  = d_in[4];
    const void* w3  = d_in[5];  const void* b3  = d_in[6];
    const void* w4  = d_in[7];  const void* b4  = d_in[8];
    const void* w5  = d_in[9];  const void* b5  = d_in[10];
    const void* w6  = d_in[11]; const void* b6  = d_in[12];
    const void* f1w = d_in[13]; const void* f1b = d_in[14];
    const void* f2w = d_in[15]; const void* f2b = d_in[16];
    const int* esrc  = (const int*)d_in[17];
    const int* edst  = (const int*)d_in[18];
    const int* batch = (const int*)d_in[19];

    char* w = (char*)d_ws;
    size_t off = 0;
    auto alloc = [&](size_t bytes) {
        void* p = w + off;
        off += (bytes + 255) & ~(size_t)255;
        return p;
    };
    int*   flag   = (int*)  alloc(256);
    int*   rs     = (int*)  alloc((size_t)(N_NODES + 1) * 4);
    float* dis    = (float*)alloc((size_t)N_NODES * 4);
    int*   csr    = (int*)  alloc((size_t)N_EDGES * 4);
    float* t      = (float*)alloc((size_t)N_NODES * 32 * 4);   // aliased by ebuf (1st half)
    float* x1     = (float*)alloc((size_t)N_NODES * 32 * 4);   // aliased by ebuf (2nd half)
    float* x2     = (float*)alloc((size_t)N_NODES * 32 * 4);
    float* x3     = (float*)alloc((size_t)N_NODES * 32 * 4);
    float* x4     = (float*)alloc((size_t)N_NODES * 4);
    int*   gstart = (int*)  alloc((size_t)(NGRAPH + 1) * 4);
    int*   sel    = (int*)  alloc((size_t)NGRAPH * KTOP * 4);
    float* Pg     = (float*)alloc((size_t)PELEM * 4);
    int*   bhistT = (int*)  alloc((size_t)NBKT * NBKT_PAD * 4);
    int*   btot   = (int*)  alloc((size_t)NBKT * 4);
    int*   bstart = (int*)  alloc((size_t)(NBKT + 1) * 4);
    (void)ws_size; (void)n_in; (void)in_sizes; (void)out_size;

    int2* ebuf = (int2*)t;   // dead until k_mm1

    hipMemsetAsync(sel, 0xFF, (size_t)NGRAPH * KTOP * 4, stream);

    int nb   = (N_NODES + 255) / 256;
    int mb32 = N_NODES / 32;
    int ab   = N_NODES / 4;
    int a1b  = N_NODES / 16;
    int pb   = (PELEM + 255) / 256;

    k_detect<<<1, 64, 0, stream>>>(w1, flag);
    k_bhist<<<NTILE, 256, 0, stream>>>(esrc, edst, bhistT);
    k_bscan<<<NBKT, 64, 0, stream>>>(bhistT, btot);
    k_btscan<<<1, 1024, 0, stream>>>(btot, bstart);
    k_bscatter<<<NTILE, 256, 0, stream>>>(esrc, edst, bhistT, bstart, ebuf);
    k_bcsr<<<NBKT, 256, 0, stream>>>(ebuf, bstart, rs, dis, csr);
    k_gstart<<<5, 256, 0, stream>>>(batch, gstart);

    k_mm1<<<mb32, 256, 0, stream>>>(x, w1, flag, dis, t);
    k_agg32<<<ab, 256, 0, stream>>>((const float4*)t, rs, csr, dis, b1, flag, (float4*)x1);
    k_mm32<<<mb32, 256, 0, stream>>>(x1, w2, flag, dis, t);
    k_agg32<<<ab, 256, 0, stream>>>((const float4*)t, rs, csr, dis, b2, flag, (float4*)x2);
    k_mm32<<<mb32, 256, 0, stream>>>(x2, w3, flag, dis, t);
    k_agg32<<<ab, 256, 0, stream>>>((const float4*)t, rs, csr, dis, b3, flag, (float4*)x3);
    k_mm_out1<<<(N_NODES + 7) / 8, 256, 0, stream>>>(x3, w4, flag, dis, t);
    k_agg1<<<a1b, 256, 0, stream>>>(t, rs, csr, dis, b4, flag, x4);
    k_rank<<<nb, 256, 0, stream>>>(batch, gstart, x4, sel);
    k_pool<<<pb, 256, 0, stream>>>(x1, x2, x3, x4, sel, Pg);
    k_head<<<NGRAPH, 128, 0, stream>>>(Pg, w5, b5, w6, b6,
                                       f1w, f1b, f2w, f2b, flag, (void*)d_out);
}

// Round 11
// 611.543 us; speedup vs baseline: 1.1198x; 1.0511x over previous
//
#include <hip/hip_runtime.h>
#include <hip/hip_bf16.h>

#define N_NODES 100000
#define N_EDGES 3200000
#define NGRAPH 1024
#define KTOP 30
#define PELEM (NGRAPH * KTOP * 97)         // pooled tensor elements

#define NBKT 782                            // ceil(100000 / 128) node buckets
#define NBKT_PAD 392                        // padded tile-count row (>= NTILE)
#define NTILE 391                           // edge tiles
#define TILE 8192                           // edges per tile (391*8192 >= 3.2M)

typedef __hip_bfloat16 bf16;

__device__ __forceinline__ float u2f(unsigned short h) {
    return __uint_as_float(((unsigned int)h) << 16);
}
// Flag-steered scalar load of a float-tensor input that may be bf16 or f32.
__device__ __forceinline__ float LD(const void* p, int i, int bf) {
    if (bf) return u2f(((const unsigned short*)p)[i]);
    return ((const float*)p)[i];
}

// ---------- dtype probe ----------
__global__ void k_detect(const void* w1, int* flag) {
    if (threadIdx.x == 0 && blockIdx.x == 0) {
        const unsigned short* u = (const unsigned short*)w1;
        int plausible = 0;
        for (int i = 0; i < 64; i++) {
            float a = fabsf(u2f(u[2 * i]));
            if (a == 0.f || (a >= 9.765625e-4f && a <= 2.0f)) plausible++;
        }
        *flag = (plausible >= 40) ? 1 : 0;
    }
}

// ---------- atomic-free bucket partition (digit = dst>>7) ----------
__global__ __launch_bounds__(256) void k_bhist(const int* __restrict__ src,
                                               const int* __restrict__ dst,
                                               int* __restrict__ bhistT) {
    __shared__ int h[NBKT];
    int blk = blockIdx.x;
    for (int i = threadIdx.x; i < NBKT; i += 256) h[i] = 0;
    __syncthreads();
    int base = blk * TILE;
    for (int i = threadIdx.x; i < TILE; i += 256) {
        int e = base + i;
        if (e < N_EDGES) {
            int s = src[e], d = dst[e];
            if (s != d) atomicAdd(&h[d >> 7], 1);
        }
    }
    __syncthreads();
    for (int i = threadIdx.x; i < NBKT; i += 256) bhistT[i * NBKT_PAD + blk] = h[i];
}

__global__ __launch_bounds__(64) void k_bscan(int* __restrict__ bhistT,
                                              int* __restrict__ btot) {
    int b = blockIdx.x;
    int lane = threadIdx.x;
    int* row = &bhistT[b * NBKT_PAD];
    int carry = 0;
    for (int c = 0; c < NTILE; c += 64) {
        int idx = c + lane;
        int v = (idx < NTILE) ? row[idx] : 0;
        int sc = v;
#pragma unroll
        for (int off = 1; off < 64; off <<= 1) {
            int t = __shfl_up(sc, off);
            if (lane >= off) sc += t;
        }
        if (idx < NTILE) row[idx] = sc - v + carry;   // exclusive + carry
        carry += __shfl(sc, 63);
    }
    if (lane == 0) btot[b] = carry;
}

__global__ void k_btscan(const int* __restrict__ btot, int* __restrict__ bstart) {
    __shared__ int sh[1024];
    int v = ((int)threadIdx.x < NBKT) ? btot[threadIdx.x] : 0;
    sh[threadIdx.x] = v;
    __syncthreads();
    for (int off = 1; off < 1024; off <<= 1) {
        int t = (threadIdx.x >= off) ? sh[threadIdx.x - off] : 0;
        __syncthreads();
        sh[threadIdx.x] += t;
        __syncthreads();
    }
    if ((int)threadIdx.x < NBKT) bstart[threadIdx.x] = sh[threadIdx.x] - v;
    if (threadIdx.x == NBKT - 1) bstart[NBKT] = sh[threadIdx.x];
}

__global__ __launch_bounds__(256) void k_bscatter(const int* __restrict__ src,
                                                  const int* __restrict__ dst,
                                                  const int* __restrict__ bhistT,
                                                  const int* __restrict__ bstart,
                                                  int2* __restrict__ ebuf) {
    __shared__ int cur[NBKT];
    int blk = blockIdx.x;
    for (int i = threadIdx.x; i < NBKT; i += 256)
        cur[i] = bstart[i] + bhistT[i * NBKT_PAD + blk];
    __syncthreads();
    int base = blk * TILE;
    for (int i = threadIdx.x; i < TILE; i += 256) {
        int e = base + i;
        if (e < N_EDGES) {
            int s = src[e], d = dst[e];
            if (s != d) {
                int p = atomicAdd(&cur[d >> 7], 1);
                ebuf[p] = make_int2(s, d);
            }
        }
    }
}

__global__ __launch_bounds__(256) void k_bcsr(const int2* __restrict__ ebuf,
                                              const int* __restrict__ bstart,
                                              int* __restrict__ rs,
                                              float* __restrict__ dis,
                                              int* __restrict__ csr) {
    __shared__ int dloc[128];
    __shared__ int sc[128];
    int b = blockIdx.x;
    int node0 = b << 7;
    int nn = N_NODES - node0; if (nn > 128) nn = 128;
    int tid = threadIdx.x;
    if (tid < 128) dloc[tid] = 0;
    __syncthreads();
    int s = bstart[b], e = bstart[b + 1];
    for (int i = s + tid; i < e; i += 256)
        atomicAdd(&dloc[ebuf[i].y - node0], 1);
    __syncthreads();
    if (tid < 128) sc[tid] = dloc[tid];
    __syncthreads();
    for (int off = 1; off < 128; off <<= 1) {
        int t = (tid >= off && tid < 128) ? sc[tid - off] : 0;
        __syncthreads();
        if (tid < 128) sc[tid] += t;
        __syncthreads();
    }
    if (tid < nn) {
        rs[node0 + tid] = s + sc[tid] - dloc[tid];
        dis[node0 + tid] = rsqrtf((float)dloc[tid] + 1.0f);
    }
    if (b == NBKT - 1 && tid == 0) rs[N_NODES] = e;
    __syncthreads();
    if (tid < 128) dloc[tid] = s + sc[tid] - dloc[tid];  // cursors
    __syncthreads();
    for (int i = s + tid; i < e; i += 256) {
        int2 p = ebuf[i];
        int pos = atomicAdd(&dloc[p.y - node0], 1);
        csr[pos] = p.x;
    }
}

__global__ void k_gstart(const int* __restrict__ batch, int* __restrict__ gstart) {
    int g = blockIdx.x * 256 + threadIdx.x;
    if (g > NGRAPH) return;
    int lo = 0, hi = N_NODES;
    while (lo < hi) {
        int mid = (lo + hi) >> 1;
        if (batch[mid] < g) lo = mid + 1; else hi = mid;
    }
    gstart[g] = lo;
}

// ---------- GCN layers (activations f32; ts = dis * (x @ W)) ----------
__global__ __launch_bounds__(256) void k_mm1(const void* __restrict__ x,
                                             const void* __restrict__ w,
                                             const int* __restrict__ flagp,
                                             const float* __restrict__ dis,
                                             float* __restrict__ ts) {
    __shared__ float Wl[128 * 32];
    __shared__ float Xs[32][128];
    int bf = *flagp;
    int tid = threadIdx.x;
    int nbase = blockIdx.x * 32;          // N_NODES % 32 == 0: always full
    if (bf) {
        const ushort4* wv = (const ushort4*)w;
        for (int idx = tid; idx < 1024; idx += 256) {
            ushort4 h = wv[idx];
            int p = idx * 4;
            Wl[p] = u2f(h.x); Wl[p + 1] = u2f(h.y); Wl[p + 2] = u2f(h.z); Wl[p + 3] = u2f(h.w);
        }
        const ushort4* xv = (const ushort4*)x;
        for (int idx = tid; idx < 1024; idx += 256) {
            int nd = idx >> 5, q = idx & 31;
            ushort4 h = xv[(size_t)(nbase + nd) * 32 + q];
            float* d = &Xs[nd][q * 4];
            d[0] = u2f(h.x); d[1] = u2f(h.y); d[2] = u2f(h.z); d[3] = u2f(h.w);
        }
    } else {
        const float* wf = (const float*)w;
        for (int idx = tid; idx < 4096; idx += 256) Wl[idx] = wf[idx];
        const float* xf = (const float*)x;
        for (int idx = tid; idx < 4096; idx += 256)
            Xs[idx >> 7][idx & 127] = xf[(size_t)nbase * 128 + idx];
    }
    __syncthreads();
    int grp = tid >> 5, col = tid & 31;
    for (int rep = 0; rep < 4; rep++) {
        int sub = grp + 8 * rep;
        int node = nbase + sub;
        float acc = 0.f;
#pragma unroll 8
        for (int k = 0; k < 128; k++) acc += Xs[sub][k] * Wl[k * 32 + col];
        ts[node * 32 + col] = dis[node] * acc;
    }
}

__global__ __launch_bounds__(256) void k_mm32(const float* __restrict__ xin,
                                              const void* __restrict__ w,
                                              const int* __restrict__ flagp,
                                              const float* __restrict__ dis,
                                              float* __restrict__ ts) {
    __shared__ float Wl[32 * 32];
    __shared__ float Xs[32][32];
    int bf = *flagp;
    int tid = threadIdx.x;
    int nbase = blockIdx.x * 32;
    if (bf) {
        const ushort4* wv = (const ushort4*)w;
        for (int idx = tid; idx < 256; idx += 256) {
            ushort4 h = wv[idx];
            int p = idx * 4;
            Wl[p] = u2f(h.x); Wl[p + 1] = u2f(h.y); Wl[p + 2] = u2f(h.z); Wl[p + 3] = u2f(h.w);
        }
    } else {
        const float* wf = (const float*)w;
        for (int idx = tid; idx < 1024; idx += 256) Wl[idx] = wf[idx];
    }
    {
        const float4* xv = (const float4*)xin;
        int nd = tid >> 3, q = tid & 7;
        float4 v = xv[(size_t)(nbase + nd) * 8 + q];
        float* d = &Xs[nd][q * 4];
        d[0] = v.x; d[1] = v.y; d[2] = v.z; d[3] = v.w;
    }
    __syncthreads();
    int grp = tid >> 5, col = tid & 31;
    for (int rep = 0; rep < 4; rep++) {
        int sub = grp + 8 * rep;
        int node = nbase + sub;
        float acc = 0.f;
#pragma unroll
        for (int k = 0; k < 32; k++) acc += Xs[sub][k] * Wl[k * 32 + col];
        ts[node * 32 + col] = dis[node] * acc;
    }
}

__global__ __launch_bounds__(256) void k_mm_out1(const float* __restrict__ xin,
                                                 const void* __restrict__ w4,
                                                 const int* __restrict__ flagp,
                                                 const float* __restrict__ dis,
                                                 float* __restrict__ ts4) {
    int node = blockIdx.x * 8 + (threadIdx.x >> 5);
    int lane = threadIdx.x & 31;
    if (node >= N_NODES) return;
    int bf = *flagp;
    float v = xin[node * 32 + lane] * LD(w4, lane, bf);
    for (int off = 16; off; off >>= 1) v += __shfl_down(v, off, 32);
    if (lane == 0) ts4[node] = dis[node] * v;
}

// One wave64 per node; 8 lanes per row (float4/lane); gather loop unrolled x4
// => up to 32 neighbor rows in flight per wave.
__global__ __launch_bounds__(256) void k_agg32(const float4* __restrict__ ts,
                                               const int* __restrict__ rs,
                                               const int* __restrict__ csr,
                                               const float* __restrict__ dis,
                                               const void* __restrict__ b,
                                               const int* __restrict__ flagp,
                                               float4* __restrict__ out) {
    int node = blockIdx.x * 4 + (threadIdx.x >> 6);
    int lane = threadIdx.x & 63;
    int q   = lane & 7;
    int grp = lane >> 3;
    int bf = *flagp;
    int s = rs[node], e = rs[node + 1];
    float4 a0 = make_float4(0.f, 0.f, 0.f, 0.f);
    float4 a1 = a0, a2 = a0, a3 = a0;
    int i = s + grp;
    for (; i + 24 < e; i += 32) {
        int v0 = csr[i], v1 = csr[i + 8], v2 = csr[i + 16], v3 = csr[i + 24];
        float4 m0 = ts[v0 * 8 + q];
        float4 m1 = ts[v1 * 8 + q];
        float4 m2 = ts[v2 * 8 + q];
        float4 m3 = ts[v3 * 8 + q];
        a0.x += m0.x; a0.y += m0.y; a0.z += m0.z; a0.w += m0.w;
        a1.x += m1.x; a1.y += m1.y; a1.z += m1.z; a1.w += m1.w;
        a2.x += m2.x; a2.y += m2.y; a2.z += m2.z; a2.w += m2.w;
        a3.x += m3.x; a3.y += m3.y; a3.z += m3.z; a3.w += m3.w;
    }
    for (; i < e; i += 8) {
        float4 m = ts[csr[i] * 8 + q];
        a0.x += m.x; a0.y += m.y; a0.z += m.z; a0.w += m.w;
    }
    float4 acc;
    acc.x = (a0.x + a1.x) + (a2.x + a3.x);
    acc.y = (a0.y + a1.y) + (a2.y + a3.y);
    acc.z = (a0.z + a1.z) + (a2.z + a3.z);
    acc.w = (a0.w + a1.w) + (a2.w + a3.w);
#pragma unroll
    for (int off = 8; off < 64; off <<= 1) {
        acc.x += __shfl_xor(acc.x, off);
        acc.y += __shfl_xor(acc.y, off);
        acc.z += __shfl_xor(acc.z, off);
        acc.w += __shfl_xor(acc.w, off);
    }
    if (grp == 0) {
        float4 self = ts[node * 8 + q];
        float d = dis[node];
        float4 r;
        r.x = tanhf(d * (acc.x + self.x) + LD(b, q * 4 + 0, bf));
        r.y = tanhf(d * (acc.y + self.y) + LD(b, q * 4 + 1, bf));
        r.z = tanhf(d * (acc.z + self.z) + LD(b, q * 4 + 2, bf));
        r.w = tanhf(d * (acc.w + self.w) + LD(b, q * 4 + 3, bf));
        out[node * 8 + q] = r;
    }
}

// 16 lanes per node.
__global__ __launch_bounds__(256) void k_agg1(const float* __restrict__ ts4,
                                              const int* __restrict__ rs,
                                              const int* __restrict__ csr,
                                              const float* __restrict__ dis,
                                              const void* __restrict__ b4,
                                              const int* __restrict__ flagp,
                                              float* __restrict__ x4) {
    int node = blockIdx.x * 16 + (threadIdx.x >> 4);
    int lane = threadIdx.x & 15;
    int s = rs[node], e = rs[node + 1];
    float acc = 0.f;
    for (int i = s + lane; i < e; i += 16) acc += ts4[csr[i]];
#pragma unroll
    for (int off = 1; off < 16; off <<= 1) acc += __shfl_xor(acc, off);
    if (lane == 0) {
        int bf = *flagp;
        x4[node] = tanhf(dis[node] * (acc + ts4[node]) + LD(b4, 0, bf));
    }
}

// ---------- SortPooling rank ----------
__global__ __launch_bounds__(256) void k_rank(const int* __restrict__ batch,
                                              const int* __restrict__ gstart,
                                              const float* __restrict__ x4,
                                              int* __restrict__ sel) {
    int i = blockIdx.x * 256 + threadIdx.x;
    if (i >= N_NODES) return;
    int g = batch[i];
    int s = gstart[g], e = gstart[g + 1];
    float ki = x4[i];
    int rank = 0;
    for (int j = s; j < e; j++) {
        float kj = x4[j];
        rank += (kj > ki) || (kj == ki && j < i);
    }
    if (rank < KTOP) sel[g * KTOP + rank] = i;
}

// ---------- Pooled-tensor gather ----------
__global__ __launch_bounds__(256) void k_pool(const float* __restrict__ x1,
                                              const float* __restrict__ x2,
                                              const float* __restrict__ x3,
                                              const float* __restrict__ x4,
                                              const int* __restrict__ sel,
                                              float* __restrict__ P) {
    int idx = blockIdx.x * 256 + threadIdx.x;
    if (idx >= PELEM) return;
    int g = idx / (KTOP * 97);
    int r = idx - g * (KTOP * 97);
    int p = r / 97;
    int f = r - p * 97;
    int v = sel[g * KTOP + p];
    float val = 0.f;
    if (v >= 0) {
        if (f < 32)      val = x1[v * 32 + f];
        else if (f < 64) val = x2[v * 32 + f - 32];
        else if (f < 96) val = x3[v * 32 + f - 64];
        else             val = x4[v];
    }
    P[idx] = val;
}

// ---------- CNN/MLP head: 256 threads, SIMPLE single-acc loops.
// Round-9 lesson: 4-way ILP + fc1 split => VGPR 132, occ 11%, 133 us. Keep
// per-thread register footprint small; win comes from 16 waves/CU vs 8. ----------
__global__ __launch_bounds__(256) void k_head(
    const float* __restrict__ Pg,
    const void* __restrict__ w5, const void* __restrict__ b5,
    const void* __restrict__ w6, const void* __restrict__ b6,
    const void* __restrict__ f1w, const void* __restrict__ f1b,
    const void* __restrict__ f2w, const void* __restrict__ f2b,
    const int* __restrict__ flagp, void* __restrict__ out) {
    __shared__ float P[KTOP * 97];
    __shared__ float W5[16 * 97];
    __shared__ float W6[32 * 16 * 5];
    __shared__ float H5[16][30];
    __shared__ float M[16][15];
    __shared__ float H6[352];
    __shared__ float Rp[256];
    __shared__ float R1[128];
    __shared__ float L[10];
    __shared__ float mls;
    int g = blockIdx.x;
    int tid = threadIdx.x;
    int bf = *flagp;

    for (int i = tid; i < KTOP * 97; i += 256) P[i] = Pg[g * (KTOP * 97) + i];
    if (bf) {   // vectorized bf16 weight staging
        const ushort4* w5v = (const ushort4*)w5;
        for (int i = tid; i < 388; i += 256) {           // 1552 = 388*4
            ushort4 h = w5v[i];
            int p = i * 4;
            W5[p] = u2f(h.x); W5[p + 1] = u2f(h.y); W5[p + 2] = u2f(h.z); W5[p + 3] = u2f(h.w);
        }
        const ushort4* w6v = (const ushort4*)w6;
        for (int i = tid; i < 640; i += 256) {           // 2560 = 640*4
            ushort4 h = w6v[i];
            int p = i * 4;
            W6[p] = u2f(h.x); W6[p + 1] = u2f(h.y); W6[p + 2] = u2f(h.z); W6[p + 3] = u2f(h.w);
        }
    } else {
        for (int i = tid; i < 16 * 97; i += 256) W5[i] = ((const float*)w5)[i];
        for (int i = tid; i < 2560; i += 256) W6[i] = ((const float*)w6)[i];
    }
    __syncthreads();
    for (int idx = tid; idx < 480; idx += 256) {   // conv5 + relu
        int o = idx / 30, p = idx - o * 30;
        float acc = LD(b5, o, bf);
        const float* pr = &P[p * 97];
        const float* wr = &W5[o * 97];
        for (int f = 0; f < 97; f++) acc += wr[f] * pr[f];
        H5[o][p] = fmaxf(acc, 0.f);
    }
    __syncthreads();
    for (int idx = tid; idx < 240; idx += 256) {   // maxpool2
        int o = idx / 15, q = idx - o * 15;
        M[o][q] = fmaxf(H5[o][2 * q], H5[o][2 * q + 1]);
    }
    __syncthreads();
    for (int idx = tid; idx < 352; idx += 256) {   // conv6 + relu
        int oc = idx / 11, tp = idx - oc * 11;
        float acc = LD(b6, oc, bf);
        const float* wr = &W6[oc * 80];
        for (int ic = 0; ic < 16; ic++) {
#pragma unroll
            for (int k = 0; k < 5; k++)
                acc += wr[ic * 5 + k] * M[ic][tp + k];
        }
        H6[idx] = fmaxf(acc, 0.f);
    }
    __syncthreads();
    {   // fc1: 2 threads per output column, 176 terms each, single accumulator
        int half = tid >> 7, col = tid & 127;
        int base = half * 176;
        float a = 0.f;
        for (int i = 0; i < 176; i++) {
            int ii = base + i;
            a += H6[ii] * LD(f1w, ii * 128 + col, bf);
        }
        Rp[tid] = a;
    }
    __syncthreads();
    if (tid < 128) R1[tid] = fmaxf(LD(f1b, tid, bf) + Rp[tid] + Rp[128 + tid], 0.f);
    __syncthreads();
    if (tid < 10) {   // fc2
        float acc = LD(f2b, tid, bf);
        for (int k = 0; k < 128; k++) acc += R1[k] * LD(f2w, k * 10 + tid, bf);
        L[tid] = acc;
    }
    __syncthreads();
    if (tid == 0) {
        float m = L[0];
        for (int c = 1; c < 10; c++) m = fmaxf(m, L[c]);
        float ssum = 0.f;
        for (int c = 0; c < 10; c++) ssum += expf(L[c] - m);
        mls = m + logf(ssum);
    }
    __syncthreads();
    if (tid < 10) {
        float v = L[tid] - mls;
        if (bf) ((bf16*)out)[g * 10 + tid] = __float2bfloat16(v);
        else    ((float*)out)[g * 10 + tid] = v;
    }
}

extern "C" void kernel_launch(void* const* d_in, const int* in_sizes, int n_in,
                              void* d_out, int out_size, void* d_ws, size_t ws_size,
                              hipStream_t stream) {
    const void* x   = d_in[0];
    const void* w1  = d_in[1];  const void* b1  = d_in[2];
    const void* w2  = d_in[3];  const void* b2  = d_in[4];
    const void* w3  = d_in[5];  const void* b3  = d_in[6];
    const void* w4  = d_in[7];  const void* b4  = d_in[8];
    const void* w5  = d_in[9];  const void* b5  = d_in[10];
    const void* w6  = d_in[11]; const void* b6  = d_in[12];
    const void* f1w = d_in[13]; const void* f1b = d_in[14];
    const void* f2w = d_in[15]; const void* f2b = d_in[16];
    const int* esrc  = (const int*)d_in[17];
    const int* edst  = (const int*)d_in[18];
    const int* batch = (const int*)d_in[19];

    char* w = (char*)d_ws;
    size_t off = 0;
    auto alloc = [&](size_t bytes) {
        void* p = w + off;
        off += (bytes + 255) & ~(size_t)255;
        return p;
    };
    int*   flag   = (int*)  alloc(256);
    int*   rs     = (int*)  alloc((size_t)(N_NODES + 1) * 4);
    float* dis    = (float*)alloc((size_t)N_NODES * 4);
    int*   csr    = (int*)  alloc((size_t)N_EDGES * 4);
    float* t      = (float*)alloc((size_t)N_NODES * 32 * 4);   // aliased by ebuf (1st half)
    float* x1     = (float*)alloc((size_t)N_NODES * 32 * 4);   // aliased by ebuf (2nd half)
    float* x2     = (float*)alloc((size_t)N_NODES * 32 * 4);
    float* x3     = (float*)alloc((size_t)N_NODES * 32 * 4);
    float* x4     = (float*)alloc((size_t)N_NODES * 4);
    int*   gstart = (int*)  alloc((size_t)(NGRAPH + 1) * 4);
    int*   sel    = (int*)  alloc((size_t)NGRAPH * KTOP * 4);
    float* Pg     = (float*)alloc((size_t)PELEM * 4);
    int*   bhistT = (int*)  alloc((size_t)NBKT * NBKT_PAD * 4);
    int*   btot   = (int*)  alloc((size_t)NBKT * 4);
    int*   bstart = (int*)  alloc((size_t)(NBKT + 1) * 4);
    (void)ws_size; (void)n_in; (void)in_sizes; (void)out_size;

    int2* ebuf = (int2*)t;   // dead until k_mm1

    hipMemsetAsync(sel, 0xFF, (size_t)NGRAPH * KTOP * 4, stream);

    int nb   = (N_NODES + 255) / 256;
    int mb32 = N_NODES / 32;
    int ab   = N_NODES / 4;
    int a1b  = N_NODES / 16;
    int pb   = (PELEM + 255) / 256;

    k_detect<<<1, 64, 0, stream>>>(w1, flag);
    k_bhist<<<NTILE, 256, 0, stream>>>(esrc, edst, bhistT);
    k_bscan<<<NBKT, 64, 0, stream>>>(bhistT, btot);
    k_btscan<<<1, 1024, 0, stream>>>(btot, bstart);
    k_bscatter<<<NTILE, 256, 0, stream>>>(esrc, edst, bhistT, bstart, ebuf);
    k_bcsr<<<NBKT, 256, 0, stream>>>(ebuf, bstart, rs, dis, csr);
    k_gstart<<<5, 256, 0, stream>>>(batch, gstart);

    k_mm1<<<mb32, 256, 0, stream>>>(x, w1, flag, dis, t);
    k_agg32<<<ab, 256, 0, stream>>>((const float4*)t, rs, csr, dis, b1, flag, (float4*)x1);
    k_mm32<<<mb32, 256, 0, stream>>>(x1, w2, flag, dis, t);
    k_agg32<<<ab, 256, 0, stream>>>((const float4*)t, rs, csr, dis, b2, flag, (float4*)x2);
    k_mm32<<<mb32, 256, 0, stream>>>(x2, w3, flag, dis, t);
    k_agg32<<<ab, 256, 0, stream>>>((const float4*)t, rs, csr, dis, b3, flag, (float4*)x3);
    k_mm_out1<<<(N_NODES + 7) / 8, 256, 0, stream>>>(x3, w4, flag, dis, t);
    k_agg1<<<a1b, 256, 0, stream>>>(t, rs, csr, dis, b4, flag, x4);
    k_rank<<<nb, 256, 0, stream>>>(batch, gstart, x4, sel);
    k_pool<<<pb, 256, 0, stream>>>(x1, x2, x3, x4, sel, Pg);
    k_head<<<NGRAPH, 256, 0, stream>>>(Pg, w5, b5, w6, b6,
                                       f1w, f1b, f2w, f2b, flag, (void*)d_out);
}